// Round 1
// baseline (12285.738 us; speedup 1.0000x reference)
//
#include <hip/hip_runtime.h>
#include <cstdint>
#include <cstddef>

#define D 128
#define RR 8

// ---------------------------------------------------------------------------
// Generic fp32 GEMM: C[M,BN] = A[M,128] @ B[128,BN] (+bias) (+relu)
// block: 256 threads, tile 128 x BN, per-thread 8 x (BN/16) outputs.
// K=128 processed in 4 chunks of 32; A transposed into LDS for float4 reads.
// ---------------------------------------------------------------------------
template<int BN, bool BIAS, bool RELU>
__global__ __launch_bounds__(256) void gemm_k128(
    const float* __restrict__ A, const float* __restrict__ B,
    const float* __restrict__ bias, float* __restrict__ C, int M)
{
    constexpr int TN = BN / 16;           // 8 (BN=128) or 4 (BN=64)
    __shared__ float As[32][128];         // [k][m]
    __shared__ float Bs[32][BN];          // [k][n]

    const int tid = threadIdx.x;
    const int tx = tid & 15, ty = tid >> 4;
    const int m0 = blockIdx.x * 128;

    float acc[8][TN];
#pragma unroll
    for (int i = 0; i < 8; i++)
#pragma unroll
        for (int j = 0; j < TN; j++) acc[i][j] = 0.f;

    const int lrow = tid >> 1;            // 0..127
    const int lkq  = (tid & 1) * 16;      // 0 or 16
    const int gr   = m0 + lrow;

    for (int kc = 0; kc < 128; kc += 32) {
        // ---- stage A chunk (transposed) ----
        float av[16];
        if (gr < M) {
            const float4* ap = (const float4*)(A + (size_t)gr * 128 + kc + lkq);
            float4 v0 = ap[0], v1 = ap[1], v2 = ap[2], v3 = ap[3];
            av[0]=v0.x; av[1]=v0.y; av[2]=v0.z; av[3]=v0.w;
            av[4]=v1.x; av[5]=v1.y; av[6]=v1.z; av[7]=v1.w;
            av[8]=v2.x; av[9]=v2.y; av[10]=v2.z; av[11]=v2.w;
            av[12]=v3.x; av[13]=v3.y; av[14]=v3.z; av[15]=v3.w;
        } else {
#pragma unroll
            for (int i = 0; i < 16; i++) av[i] = 0.f;
        }
#pragma unroll
        for (int i = 0; i < 16; i++) As[lkq + i][lrow] = av[i];

        // ---- stage B chunk (natural layout, coalesced float4) ----
        {
            const float4* bp = (const float4*)(B + (size_t)kc * BN);
            float4* bs = (float4*)(&Bs[0][0]);
            constexpr int NV = (32 * BN / 4) / 256;   // 4 or 2
#pragma unroll
            for (int q = 0; q < NV; q++) bs[tid + 256 * q] = bp[tid + 256 * q];
        }
        __syncthreads();

#pragma unroll
        for (int k = 0; k < 32; k++) {
            float4 a0 = *(const float4*)(&As[k][ty * 4]);
            float4 a1 = *(const float4*)(&As[k][64 + ty * 4]);
            float a[8] = {a0.x, a0.y, a0.z, a0.w, a1.x, a1.y, a1.z, a1.w};
            float b[TN];
            {
                float4 b0 = *(const float4*)(&Bs[k][tx * 4]);
                b[0]=b0.x; b[1]=b0.y; b[2]=b0.z; b[3]=b0.w;
                if constexpr (TN == 8) {
                    float4 b1 = *(const float4*)(&Bs[k][64 + tx * 4]);
                    b[4]=b1.x; b[5]=b1.y; b[6]=b1.z; b[7]=b1.w;
                }
            }
#pragma unroll
            for (int i = 0; i < 8; i++)
#pragma unroll
                for (int j = 0; j < TN; j++)
                    acc[i][j] += a[i] * b[j];
        }
        __syncthreads();
    }

    // ---- epilogue ----
#pragma unroll
    for (int i = 0; i < 8; i++) {
        int grr = m0 + (i < 4 ? ty * 4 + i : 64 + ty * 4 + (i - 4));
        if (grr < M) {
            float* cp = C + (size_t)grr * BN + tx * 4;
            float4 v;
            v.x = acc[i][0]; v.y = acc[i][1]; v.z = acc[i][2]; v.w = acc[i][3];
            if (BIAS) {
                v.x += bias[tx*4+0]; v.y += bias[tx*4+1];
                v.z += bias[tx*4+2]; v.w += bias[tx*4+3];
            }
            if (RELU) {
                v.x = v.x > 0.f ? v.x : 0.f; v.y = v.y > 0.f ? v.y : 0.f;
                v.z = v.z > 0.f ? v.z : 0.f; v.w = v.w > 0.f ? v.w : 0.f;
            }
            *(float4*)cp = v;
            if constexpr (TN == 8) {
                float4 w;
                w.x = acc[i][4]; w.y = acc[i][5]; w.z = acc[i][6]; w.w = acc[i][7];
                if (BIAS) {
                    w.x += bias[64+tx*4+0]; w.y += bias[64+tx*4+1];
                    w.z += bias[64+tx*4+2]; w.w += bias[64+tx*4+3];
                }
                if (RELU) {
                    w.x = w.x > 0.f ? w.x : 0.f; w.y = w.y > 0.f ? w.y : 0.f;
                    w.z = w.z > 0.f ? w.z : 0.f; w.w = w.w > 0.f ? w.w : 0.f;
                }
                *(float4*)(cp + 64) = w;
            }
        }
    }
}

// ---------------------------------------------------------------------------
// W[r][d][f] = sum_b comp[r][b] * basis[b][d][f]
// ---------------------------------------------------------------------------
__global__ void combine_W(const float* __restrict__ basis,
                          const float* __restrict__ comp,
                          float* __restrict__ W)
{
    int i = blockIdx.x * 256 + threadIdx.x;
    if (i >= RR * D * D) return;
    int r = i >> 14;          // / (128*128)
    int df = i & 16383;
    float a = 0.f;
#pragma unroll
    for (int b = 0; b < 4; b++) a += comp[r * 4 + b] * basis[b * 16384 + df];
    W[i] = a;
}

// ---------------------------------------------------------------------------
// per-(dst,rel) counts and per-src out-degree
// ---------------------------------------------------------------------------
__global__ void count_edges(const int* __restrict__ src, const int* __restrict__ dst,
                            const int* __restrict__ et, int* __restrict__ cnt,
                            int* __restrict__ deg, int E)
{
    int e = blockIdx.x * blockDim.x + threadIdx.x;
    if (e < E) {
        atomicAdd(&cnt[dst[e] * RR + et[e]], 1);
        atomicAdd(&deg[src[e]], 1);
    }
}

__global__ void make_inv(const int* __restrict__ c, float* __restrict__ inv, int n)
{
    int i = blockIdx.x * blockDim.x + threadIdx.x;
    if (i < n) {
        int v = c[i]; if (v < 1) v = 1;
        inv[i] = 1.f / (float)v;
    }
}

// ---------------------------------------------------------------------------
// bin edges by relation (order within bin arbitrary)
// ---------------------------------------------------------------------------
__global__ void bin_count(const int* __restrict__ et, int* __restrict__ bc, int E)
{
    __shared__ int h[RR];
    if (threadIdx.x < RR) h[threadIdx.x] = 0;
    __syncthreads();
    for (int e = blockIdx.x * blockDim.x + threadIdx.x; e < E;
         e += gridDim.x * blockDim.x)
        atomicAdd(&h[et[e]], 1);
    __syncthreads();
    if (threadIdx.x < RR) atomicAdd(&bc[threadIdx.x], h[threadIdx.x]);
}

__global__ void bin_scan(const int* __restrict__ bc, int* __restrict__ boff,
                         int* __restrict__ cur)
{
    if (threadIdx.x == 0 && blockIdx.x == 0) {
        int s = 0;
        for (int r = 0; r < RR; r++) { boff[r] = s; cur[r] = s; s += bc[r]; }
        boff[RR] = s;
    }
}

__global__ void bin_fill(const int* __restrict__ src, const int* __restrict__ dst,
                         const int* __restrict__ et, int* __restrict__ cur,
                         int* __restrict__ bsrc, int* __restrict__ bdst, int E)
{
    __shared__ int lcnt[RR];
    __shared__ int base[RR];
    const int t = threadIdx.x;
    if (t < RR) lcnt[t] = 0;
    __syncthreads();
    const int e0 = blockIdx.x * 1024;
#pragma unroll
    for (int i = 0; i < 4; i++) {
        int e = e0 + t + i * 256;
        if (e < E) atomicAdd(&lcnt[et[e]], 1);
    }
    __syncthreads();
    if (t < RR) { base[t] = atomicAdd(&cur[t], lcnt[t]); lcnt[t] = 0; }
    __syncthreads();
#pragma unroll
    for (int i = 0; i < 4; i++) {
        int e = e0 + t + i * 256;
        if (e < E) {
            int r = et[e];
            int p = base[r] + atomicAdd(&lcnt[r], 1);
            bsrc[p] = src[e];
            bdst[p] = dst[e];
        }
    }
}

// ---------------------------------------------------------------------------
// gate accumulation: s[src] += (h[src]-h[dst])^2   (P=2)
// 32 lanes per edge, float4 per lane
// ---------------------------------------------------------------------------
__global__ __launch_bounds__(256) void gate_acc(
    const float* __restrict__ h, const int* __restrict__ src,
    const int* __restrict__ dst, float* __restrict__ s, int E)
{
    const int g = threadIdx.x >> 5, lane = threadIdx.x & 31;
    const int e = blockIdx.x * 8 + g;
    if (e >= E) return;
    const int si = src[e], di = dst[e];
    const float4 a = *(const float4*)(h + (size_t)si * D + lane * 4);
    const float4 b = *(const float4*)(h + (size_t)di * D + lane * 4);
    float dx = a.x - b.x, dy = a.y - b.y, dz = a.z - b.z, dw = a.w - b.w;
    float* sp = s + (size_t)si * D + lane * 4;
    atomicAdd(sp + 0, dx * dx);
    atomicAdd(sp + 1, dy * dy);
    atomicAdd(sp + 2, dz * dz);
    atomicAdd(sp + 3, dw * dw);
}

// ---------------------------------------------------------------------------
// RGCN scatter for relation r: acc[dst] += Y[src] * inv_cnt[dst, r]
// ---------------------------------------------------------------------------
__global__ __launch_bounds__(256) void rgcn_scatter(
    const float* __restrict__ Y, const int* __restrict__ bsrc,
    const int* __restrict__ bdst, const float* __restrict__ inv_cnt,
    float* __restrict__ acc, const int* __restrict__ boff, int r)
{
    const int g = threadIdx.x >> 5, lane = threadIdx.x & 31;
    const int e0 = boff[r], e1 = boff[r + 1];
    for (int e = e0 + blockIdx.x * 8 + g; e < e1; e += gridDim.x * 8) {
        const int si = bsrc[e], di = bdst[e];
        const float w = inv_cnt[di * RR + r];
        const float4 y = *(const float4*)(Y + (size_t)si * D + lane * 4);
        float* ap = acc + (size_t)di * D + lane * 4;
        atomicAdd(ap + 0, y.x * w);
        atomicAdd(ap + 1, y.y * w);
        atomicAdd(ap + 2, y.z * w);
        atomicAdd(ap + 3, y.w * w);
    }
}

// ---------------------------------------------------------------------------
// h_next = (1-tau)*h + tau*relu(acc),  tau = tanh(s * inv_deg)
// ---------------------------------------------------------------------------
__global__ void finalize(const float* __restrict__ hp, float* __restrict__ hn,
                         const float* __restrict__ S, const float* __restrict__ invd,
                         int N)
{
    int idx = blockIdx.x * blockDim.x + threadIdx.x;
    if (idx >= N * (D / 4)) return;
    int node = idx >> 5;
    float w = invd[node];
    const float4 p = ((const float4*)hp)[idx];
    float4 a = ((float4*)hn)[idx];
    const float4 sv = ((const float4*)S)[idx];
    float4 o;
    float t;
    t = tanhf(sv.x * w); a.x = a.x > 0.f ? a.x : 0.f; o.x = p.x + t * (a.x - p.x);
    t = tanhf(sv.y * w); a.y = a.y > 0.f ? a.y : 0.f; o.y = p.y + t * (a.y - p.y);
    t = tanhf(sv.z * w); a.z = a.z > 0.f ? a.z : 0.f; o.z = p.z + t * (a.z - p.z);
    t = tanhf(sv.w * w); a.w = a.w > 0.f ? a.w : 0.f; o.w = p.w + t * (a.w - p.w);
    ((float4*)hn)[idx] = o;
}

// ---------------------------------------------------------------------------
extern "C" void kernel_launch(void* const* d_in, const int* in_sizes, int n_in,
                              void* d_out, int out_size, void* d_ws, size_t ws_size,
                              hipStream_t stream)
{
    const float* x      = (const float*)d_in[0];
    const int*   src    = (const int*)  d_in[1];
    const int*   dst    = (const int*)  d_in[2];
    const int*   etyp   = (const int*)  d_in[3];
    const float* projW  = (const float*)d_in[4];
    const float* projb  = (const float*)d_in[5];
    const float* basis1 = (const float*)d_in[6];
    const float* comp1  = (const float*)d_in[7];
    const float* root1  = (const float*)d_in[8];
    const float* bias1  = (const float*)d_in[9];
    const float* basis2 = (const float*)d_in[10];
    const float* comp2  = (const float*)d_in[11];
    const float* root2  = (const float*)d_in[12];
    const float* bias2  = (const float*)d_in[13];
    const float* outW   = (const float*)d_in[14];
    const float* outb   = (const float*)d_in[15];

    const int N    = in_sizes[0] / D;
    const int E    = in_sizes[1];
    const int OUTD = in_sizes[15];

    float* out  = (float*)d_out;
    float* lat0 = out + (size_t)N * OUTD;
    float* lat1 = lat0 + (size_t)N * D;
    float* lat2 = lat1 + (size_t)N * D;

    // workspace layout
    float* W1      = (float*)d_ws;
    float* W2      = W1 + RR * D * D;
    float* Y       = W2 + RR * D * D;
    float* S       = Y + (size_t)N * D;
    float* inv_cnt = S + (size_t)N * D;
    float* inv_deg = inv_cnt + (size_t)N * RR;
    int* cnt_i   = (int*)(inv_deg + N);
    int* deg_i   = cnt_i + (size_t)N * RR;
    int* bsrc    = deg_i + N;
    int* bdst    = bsrc + E;
    int* bin_cnt = bdst + E;
    int* bin_off = bin_cnt + RR;
    int* bin_cur = bin_off + RR + 1;

    size_t need = (size_t)((char*)(bin_cur + RR) - (char*)d_ws);
    if (ws_size < need) return;   // fails loudly via poisoned d_out

    // zero counters (cnt_i and deg_i contiguous)
    hipMemsetAsync(cnt_i, 0, sizeof(int) * ((size_t)N * RR + N), stream);
    hipMemsetAsync(bin_cnt, 0, sizeof(int) * RR, stream);

    combine_W<<<(RR * D * D + 255) / 256, 256, 0, stream>>>(basis1, comp1, W1);
    combine_W<<<(RR * D * D + 255) / 256, 256, 0, stream>>>(basis2, comp2, W2);

    count_edges<<<(E + 255) / 256, 256, 0, stream>>>(src, dst, etyp, cnt_i, deg_i, E);
    make_inv<<<(N * RR + 255) / 256, 256, 0, stream>>>(cnt_i, inv_cnt, N * RR);
    make_inv<<<(N + 255) / 256, 256, 0, stream>>>(deg_i, inv_deg, N);

    bin_count<<<1024, 256, 0, stream>>>(etyp, bin_cnt, E);
    bin_scan<<<1, 64, 0, stream>>>(bin_cnt, bin_off, bin_cur);
    bin_fill<<<(E + 1023) / 1024, 256, 0, stream>>>(src, dst, etyp, bin_cur, bsrc, bdst, E);

    const int gblocks = (N + 127) / 128;

    // input projection: lat0 = relu(x @ projW + projb)
    gemm_k128<128, true, true><<<gblocks, 256, 0, stream>>>(x, projW, projb, lat0, N);

    const float* Ws[2]     = {W1, W2};
    const float* roots[2]  = {root1, root2};
    const float* biases[2] = {bias1, bias2};
    float* lats[3]         = {lat0, lat1, lat2};

    for (int l = 0; l < 2; l++) {
        const float* h = lats[l];
        float* hn = lats[l + 1];

        hipMemsetAsync(S, 0, sizeof(float) * (size_t)N * D, stream);
        gate_acc<<<(E + 7) / 8, 256, 0, stream>>>(h, src, dst, S, E);

        // root part (+bias) initializes the accumulator
        gemm_k128<128, true, false><<<gblocks, 256, 0, stream>>>(h, roots[l], biases[l], hn, N);

        for (int r = 0; r < RR; r++) {
            gemm_k128<128, false, false><<<gblocks, 256, 0, stream>>>(
                h, Ws[l] + (size_t)r * D * D, nullptr, Y, N);
            rgcn_scatter<<<25600, 256, 0, stream>>>(Y, bsrc, bdst, inv_cnt, hn, bin_off, r);
        }

        finalize<<<(N * (D / 4) + 255) / 256, 256, 0, stream>>>(h, hn, S, inv_deg, N);
    }

    // out = lat2 @ outW + outb
    gemm_k128<64, true, false><<<gblocks, 256, 0, stream>>>(lat2, outW, outb, out, N);
}

// Round 2
// 2333.096 us; speedup vs baseline: 5.2659x; 5.2659x over previous
//
#include <hip/hip_runtime.h>
#include <cstdint>
#include <cstddef>

#define D 128
#define RR 8

// ---------------------------------------------------------------------------
// Generic fp32 GEMM: C[M,BN] = A[M,128] @ B[128,BN] (+bias) (+relu)
// block: 256 threads, tile 128 x BN, per-thread 8 x (BN/16) outputs.
// ---------------------------------------------------------------------------
template<int BN, bool BIAS, bool RELU>
__global__ __launch_bounds__(256) void gemm_k128(
    const float* __restrict__ A, const float* __restrict__ B,
    const float* __restrict__ bias, float* __restrict__ C, int M)
{
    constexpr int TN = BN / 16;           // 8 (BN=128) or 4 (BN=64)
    __shared__ float As[32][128];         // [k][m]
    __shared__ float Bs[32][BN];          // [k][n]

    const int tid = threadIdx.x;
    const int tx = tid & 15, ty = tid >> 4;
    const int m0 = blockIdx.x * 128;

    float acc[8][TN];
#pragma unroll
    for (int i = 0; i < 8; i++)
#pragma unroll
        for (int j = 0; j < TN; j++) acc[i][j] = 0.f;

    const int lrow = tid >> 1;            // 0..127
    const int lkq  = (tid & 1) * 16;      // 0 or 16
    const int gr   = m0 + lrow;

    for (int kc = 0; kc < 128; kc += 32) {
        float av[16];
        if (gr < M) {
            const float4* ap = (const float4*)(A + (size_t)gr * 128 + kc + lkq);
            float4 v0 = ap[0], v1 = ap[1], v2 = ap[2], v3 = ap[3];
            av[0]=v0.x; av[1]=v0.y; av[2]=v0.z; av[3]=v0.w;
            av[4]=v1.x; av[5]=v1.y; av[6]=v1.z; av[7]=v1.w;
            av[8]=v2.x; av[9]=v2.y; av[10]=v2.z; av[11]=v2.w;
            av[12]=v3.x; av[13]=v3.y; av[14]=v3.z; av[15]=v3.w;
        } else {
#pragma unroll
            for (int i = 0; i < 16; i++) av[i] = 0.f;
        }
#pragma unroll
        for (int i = 0; i < 16; i++) As[lkq + i][lrow] = av[i];

        {
            const float4* bp = (const float4*)(B + (size_t)kc * BN);
            float4* bs = (float4*)(&Bs[0][0]);
            constexpr int NV = (32 * BN / 4) / 256;   // 4 or 2
#pragma unroll
            for (int q = 0; q < NV; q++) bs[tid + 256 * q] = bp[tid + 256 * q];
        }
        __syncthreads();

#pragma unroll
        for (int k = 0; k < 32; k++) {
            float4 a0 = *(const float4*)(&As[k][ty * 4]);
            float4 a1 = *(const float4*)(&As[k][64 + ty * 4]);
            float a[8] = {a0.x, a0.y, a0.z, a0.w, a1.x, a1.y, a1.z, a1.w};
            float b[TN];
            {
                float4 b0 = *(const float4*)(&Bs[k][tx * 4]);
                b[0]=b0.x; b[1]=b0.y; b[2]=b0.z; b[3]=b0.w;
                if constexpr (TN == 8) {
                    float4 b1 = *(const float4*)(&Bs[k][64 + tx * 4]);
                    b[4]=b1.x; b[5]=b1.y; b[6]=b1.z; b[7]=b1.w;
                }
            }
#pragma unroll
            for (int i = 0; i < 8; i++)
#pragma unroll
                for (int j = 0; j < TN; j++)
                    acc[i][j] += a[i] * b[j];
        }
        __syncthreads();
    }

#pragma unroll
    for (int i = 0; i < 8; i++) {
        int grr = m0 + (i < 4 ? ty * 4 + i : 64 + ty * 4 + (i - 4));
        if (grr < M) {
            float* cp = C + (size_t)grr * BN + tx * 4;
            float4 v;
            v.x = acc[i][0]; v.y = acc[i][1]; v.z = acc[i][2]; v.w = acc[i][3];
            if (BIAS) {
                v.x += bias[tx*4+0]; v.y += bias[tx*4+1];
                v.z += bias[tx*4+2]; v.w += bias[tx*4+3];
            }
            if (RELU) {
                v.x = v.x > 0.f ? v.x : 0.f; v.y = v.y > 0.f ? v.y : 0.f;
                v.z = v.z > 0.f ? v.z : 0.f; v.w = v.w > 0.f ? v.w : 0.f;
            }
            *(float4*)cp = v;
            if constexpr (TN == 8) {
                float4 w;
                w.x = acc[i][4]; w.y = acc[i][5]; w.z = acc[i][6]; w.w = acc[i][7];
                if (BIAS) {
                    w.x += bias[64+tx*4+0]; w.y += bias[64+tx*4+1];
                    w.z += bias[64+tx*4+2]; w.w += bias[64+tx*4+3];
                }
                if (RELU) {
                    w.x = w.x > 0.f ? w.x : 0.f; w.y = w.y > 0.f ? w.y : 0.f;
                    w.z = w.z > 0.f ? w.z : 0.f; w.w = w.w > 0.f ? w.w : 0.f;
                }
                *(float4*)(cp + 64) = w;
            }
        }
    }
}

// ---------------------------------------------------------------------------
__global__ void combine_W(const float* __restrict__ basis,
                          const float* __restrict__ comp,
                          float* __restrict__ W)
{
    int i = blockIdx.x * 256 + threadIdx.x;
    if (i >= RR * D * D) return;
    int r = i >> 14;
    int df = i & 16383;
    float a = 0.f;
#pragma unroll
    for (int b = 0; b < 4; b++) a += comp[r * 4 + b] * basis[b * 16384 + df];
    W[i] = a;
}

// ---------------------------------------------------------------------------
// counts: cnt[dst*R+et]++, deg[src]++
// ---------------------------------------------------------------------------
__global__ void count_edges(const int* __restrict__ src, const int* __restrict__ dst,
                            const int* __restrict__ et, int* __restrict__ cnt,
                            int* __restrict__ deg, int E)
{
    int e = blockIdx.x * blockDim.x + threadIdx.x;
    if (e < E) {
        atomicAdd(&cnt[dst[e] * RR + et[e]], 1);
        atomicAdd(&deg[src[e]], 1);
    }
}

// ---------------------------------------------------------------------------
// 3-phase exclusive scan (1024 elements per block)
// ---------------------------------------------------------------------------
__global__ void scan1(const int* __restrict__ in, int* __restrict__ bsum, int n)
{
    __shared__ int s[256];
    const int b = blockIdx.x, t = threadIdx.x;
    const int base = b * 1024;
    int v = 0;
#pragma unroll
    for (int i = 0; i < 4; i++) {
        int idx = base + t * 4 + i;
        if (idx < n) v += in[idx];
    }
    s[t] = v; __syncthreads();
    for (int off = 128; off > 0; off >>= 1) {
        if (t < off) s[t] += s[t + off];
        __syncthreads();
    }
    if (t == 0) bsum[b] = s[0];
}

__global__ void scan_top(int* __restrict__ bsum, int nb)
{
    __shared__ int s[1024];
    const int t = threadIdx.x;
    int v = (t < nb) ? bsum[t] : 0;
    s[t] = v; __syncthreads();
    for (int off = 1; off < 1024; off <<= 1) {
        int x = (t >= off) ? s[t - off] : 0;
        __syncthreads();
        s[t] += x;
        __syncthreads();
    }
    if (t < nb) bsum[t] = s[t] - v;   // exclusive
}

__global__ void scan2(const int* __restrict__ in, const int* __restrict__ bsum,
                      int* __restrict__ out, int n)
{
    __shared__ int s[256];
    const int b = blockIdx.x, t = threadIdx.x;
    const int base = b * 1024;
    int loc[4];
    int v = 0;
#pragma unroll
    for (int i = 0; i < 4; i++) {
        int idx = base + t * 4 + i;
        int x = (idx < n) ? in[idx] : 0;
        loc[i] = v; v += x;
    }
    s[t] = v; __syncthreads();
    for (int off = 1; off < 256; off <<= 1) {
        int x = (t >= off) ? s[t - off] : 0;
        __syncthreads();
        s[t] += x;
        __syncthreads();
    }
    const int add = bsum[b] + (s[t] - v);
#pragma unroll
    for (int i = 0; i < 4; i++) {
        int idx = base + t * 4 + i;
        if (idx < n) out[idx] = add + loc[i];
    }
}

// ---------------------------------------------------------------------------
// CSR fills
// ---------------------------------------------------------------------------
__global__ void fill_csrA(const int* __restrict__ src, const int* __restrict__ dst,
                          const int* __restrict__ et, const int* __restrict__ aoff,
                          int* __restrict__ acur, int* __restrict__ acsr, int E)
{
    int e = blockIdx.x * blockDim.x + threadIdx.x;
    if (e < E) {
        int seg = dst[e] * RR + et[e];
        int p = aoff[seg] + atomicAdd(&acur[seg], 1);
        acsr[p] = src[e];
    }
}

__global__ void fill_csrG(const int* __restrict__ src, const int* __restrict__ dst,
                          const int* __restrict__ goff, int* __restrict__ gcur,
                          int* __restrict__ gcsr, int E)
{
    int e = blockIdx.x * blockDim.x + threadIdx.x;
    if (e < E) {
        int s0 = src[e];
        int p = goff[s0] + atomicAdd(&gcur[s0], 1);
        gcsr[p] = dst[e];
    }
}

// ---------------------------------------------------------------------------
// gate gather: tau[n] = tanh( mean over out-edges of (h[n]-h[dst])^2 )
// 32 lanes per node, float4 per lane; no atomics.
// ---------------------------------------------------------------------------
__global__ __launch_bounds__(256) void gate_gather(
    const float* __restrict__ h, const int* __restrict__ gcsr,
    const int* __restrict__ goff, const int* __restrict__ deg,
    float* __restrict__ TAU, int N)
{
    const int g = threadIdx.x >> 5, lane = threadIdx.x & 31;
    const int n = blockIdx.x * 8 + g;
    if (n >= N) return;
    const int start = goff[n];
    const int c = deg[n];
    const float4 a = *(const float4*)(h + (size_t)n * D + lane * 4);
    float4 acc = {0.f, 0.f, 0.f, 0.f};
    for (int i = 0; i < c; i++) {
        int d = gcsr[start + i];
        const float4 b = *(const float4*)(h + (size_t)d * D + lane * 4);
        float dx = a.x - b.x, dy = a.y - b.y, dz = a.z - b.z, dw = a.w - b.w;
        acc.x += dx * dx; acc.y += dy * dy; acc.z += dz * dz; acc.w += dw * dw;
    }
    const float inv = (c > 0) ? (1.f / (float)c) : 1.f;
    float4 t;
    t.x = tanhf(acc.x * inv); t.y = tanhf(acc.y * inv);
    t.z = tanhf(acc.z * inv); t.w = tanhf(acc.w * inv);
    *(float4*)(TAU + (size_t)n * D + lane * 4) = t;
}

// ---------------------------------------------------------------------------
// rgcn gather for relation r: hn[n] += mean_{e in seg(n,r)} Y[src_e]
// 32 lanes per node; single-owner RMW, no atomics.
// ---------------------------------------------------------------------------
__global__ __launch_bounds__(256) void rgcn_gather(
    const float* __restrict__ Y, const int* __restrict__ acsr,
    const int* __restrict__ aoff, const int* __restrict__ cnt,
    float* __restrict__ hn, int r, int N)
{
    const int g = threadIdx.x >> 5, lane = threadIdx.x & 31;
    const int n = blockIdx.x * 8 + g;
    if (n >= N) return;
    const int seg = n * RR + r;
    const int c = cnt[seg];
    if (c == 0) return;
    const int start = aoff[seg];
    float4 acc = {0.f, 0.f, 0.f, 0.f};
    for (int i = 0; i < c; i++) {
        int s0 = acsr[start + i];
        const float4 y = *(const float4*)(Y + (size_t)s0 * D + lane * 4);
        acc.x += y.x; acc.y += y.y; acc.z += y.z; acc.w += y.w;
    }
    const float inv = 1.f / (float)c;
    float* p = hn + (size_t)n * D + lane * 4;
    float4 cur = *(float4*)p;
    cur.x += acc.x * inv; cur.y += acc.y * inv;
    cur.z += acc.z * inv; cur.w += acc.w * inv;
    *(float4*)p = cur;
}

// ---------------------------------------------------------------------------
// h_next = (1-tau)*h + tau*relu(acc)
// ---------------------------------------------------------------------------
__global__ void finalize(const float* __restrict__ hp, float* __restrict__ hn,
                         const float* __restrict__ TAU, int total4)
{
    int idx = blockIdx.x * blockDim.x + threadIdx.x;
    if (idx >= total4) return;
    const float4 p = ((const float4*)hp)[idx];
    float4 a = ((float4*)hn)[idx];
    const float4 t = ((const float4*)TAU)[idx];
    float4 o;
    a.x = a.x > 0.f ? a.x : 0.f; o.x = p.x + t.x * (a.x - p.x);
    a.y = a.y > 0.f ? a.y : 0.f; o.y = p.y + t.y * (a.y - p.y);
    a.z = a.z > 0.f ? a.z : 0.f; o.z = p.z + t.z * (a.z - p.z);
    a.w = a.w > 0.f ? a.w : 0.f; o.w = p.w + t.w * (a.w - p.w);
    ((float4*)hn)[idx] = o;
}

// ---------------------------------------------------------------------------
extern "C" void kernel_launch(void* const* d_in, const int* in_sizes, int n_in,
                              void* d_out, int out_size, void* d_ws, size_t ws_size,
                              hipStream_t stream)
{
    const float* x      = (const float*)d_in[0];
    const int*   src    = (const int*)  d_in[1];
    const int*   dst    = (const int*)  d_in[2];
    const int*   etyp   = (const int*)  d_in[3];
    const float* projW  = (const float*)d_in[4];
    const float* projb  = (const float*)d_in[5];
    const float* basis1 = (const float*)d_in[6];
    const float* comp1  = (const float*)d_in[7];
    const float* root1  = (const float*)d_in[8];
    const float* bias1  = (const float*)d_in[9];
    const float* basis2 = (const float*)d_in[10];
    const float* comp2  = (const float*)d_in[11];
    const float* root2  = (const float*)d_in[12];
    const float* bias2  = (const float*)d_in[13];
    const float* outW   = (const float*)d_in[14];
    const float* outb   = (const float*)d_in[15];

    const int N    = in_sizes[0] / D;
    const int E    = in_sizes[1];
    const int OUTD = in_sizes[15];

    float* out  = (float*)d_out;
    float* lat0 = out + (size_t)N * OUTD;
    float* lat1 = lat0 + (size_t)N * D;
    float* lat2 = lat1 + (size_t)N * D;

    // ---- workspace layout ----
    float* W1   = (float*)d_ws;              // R*D*D
    float* W2   = W1 + (size_t)RR * D * D;   // R*D*D
    float* Y    = W2 + (size_t)RR * D * D;   // N*D
    float* S    = Y + (size_t)N * D;         // N*D (tau)
    int* cnt_i  = (int*)(S + (size_t)N * D); // N*R
    int* deg_i  = cnt_i + (size_t)N * RR;    // N
    int* acur   = deg_i + N;                 // N*R
    int* gcur   = acur + (size_t)N * RR;     // N
    int* aoff   = gcur + N;                  // N*R
    int* goff   = aoff + (size_t)N * RR;     // N
    int* acsr   = goff + N;                  // E
    int* gcsr   = acsr + E;                  // E
    int* bsum   = gcsr + E;                  // 1024

    size_t need = (size_t)((char*)(bsum + 1024) - (char*)d_ws);
    if (ws_size < need) return;

    // zero counters: cnt_i, deg_i, acur, gcur contiguous
    hipMemsetAsync(cnt_i, 0, sizeof(int) * 2 * ((size_t)N * RR + N), stream);

    combine_W<<<(RR * D * D + 255) / 256, 256, 0, stream>>>(basis1, comp1, W1);
    combine_W<<<(RR * D * D + 255) / 256, 256, 0, stream>>>(basis2, comp2, W2);

    count_edges<<<(E + 255) / 256, 256, 0, stream>>>(src, dst, etyp, cnt_i, deg_i, E);

    // exclusive scans -> CSR offsets
    {
        int n1 = N * RR, nb1 = (n1 + 1023) / 1024;
        scan1<<<nb1, 256, 0, stream>>>(cnt_i, bsum, n1);
        scan_top<<<1, 1024, 0, stream>>>(bsum, nb1);
        scan2<<<nb1, 256, 0, stream>>>(cnt_i, bsum, aoff, n1);
        int nb2 = (N + 1023) / 1024;
        scan1<<<nb2, 256, 0, stream>>>(deg_i, bsum, N);
        scan_top<<<1, 1024, 0, stream>>>(bsum, nb2);
        scan2<<<nb2, 256, 0, stream>>>(deg_i, bsum, goff, N);
    }

    fill_csrA<<<(E + 255) / 256, 256, 0, stream>>>(src, dst, etyp, aoff, acur, acsr, E);
    fill_csrG<<<(E + 255) / 256, 256, 0, stream>>>(src, dst, goff, gcur, gcsr, E);

    const int gblocks = (N + 127) / 128;
    const int nodeblocks = (N + 7) / 8;

    // input projection: lat0 = relu(x @ projW + projb)
    gemm_k128<128, true, true><<<gblocks, 256, 0, stream>>>(x, projW, projb, lat0, N);

    const float* Ws[2]     = {W1, W2};
    const float* roots[2]  = {root1, root2};
    const float* biases[2] = {bias1, bias2};
    float* lats[3]         = {lat0, lat1, lat2};

    for (int l = 0; l < 2; l++) {
        const float* h = lats[l];
        float* hn = lats[l + 1];

        gate_gather<<<nodeblocks, 256, 0, stream>>>(h, gcsr, goff, deg_i, S, N);

        // root part (+bias) initializes the accumulator
        gemm_k128<128, true, false><<<gblocks, 256, 0, stream>>>(h, roots[l], biases[l], hn, N);

        for (int r = 0; r < RR; r++) {
            gemm_k128<128, false, false><<<gblocks, 256, 0, stream>>>(
                h, Ws[l] + (size_t)r * D * D, nullptr, Y, N);
            rgcn_gather<<<nodeblocks, 256, 0, stream>>>(Y, acsr, aoff, cnt_i, hn, r, N);
        }

        finalize<<<(N * (D / 4) + 255) / 256, 256, 0, stream>>>(h, hn, S, N * (D / 4));
    }

    // out = lat2 @ outW + outb
    gemm_k128<64, true, false><<<gblocks, 256, 0, stream>>>(lat2, outW, outb, out, N);
}

// Round 3
// 1668.714 us; speedup vs baseline: 7.3624x; 1.3981x over previous
//
#include <hip/hip_runtime.h>
#include <cstdint>
#include <cstddef>

#define D 128
#define RR 8

typedef __attribute__((ext_vector_type(8))) short short8;
typedef __attribute__((ext_vector_type(4))) float f32x4;

__device__ inline ushort f2b(float x) {
    union { float f; unsigned u; } v; v.f = x;
    unsigned r = v.u + 0x7fff + ((v.u >> 16) & 1);
    return (ushort)(r >> 16);
}
__device__ inline float b2f(ushort u) {
    union { unsigned u; float f; } v; v.u = ((unsigned)u) << 16; return v.f;
}

// ---------------------------------------------------------------------------
// bf16 MFMA GEMM: C[M, ncol] = A[M,128] @ B (+bias) (+relu)
// A: [M][128] bf16 row-major.  BT: [ntiles*128][128] bf16, row n = output col.
// 256 threads = 4 waves; block tile 128(M) x 128(N); K=128 in 4 mfma steps.
// LDS XOR-swizzled on 16B groups to kill bank conflicts (64KB total).
// In-place A==Cb is safe for gridDim.y==1 (each block touches only its rows).
// ---------------------------------------------------------------------------
template<bool BIAS, bool RELU, bool STF, bool STB>
__global__ __launch_bounds__(256) void gemm_bf16(
    const ushort* __restrict__ A, const ushort* __restrict__ BT,
    const float* __restrict__ bias, float* __restrict__ Cf,
    ushort* __restrict__ Cb, int M, int ldc, int ncol)
{
    __shared__ ushort As[128 * 128];
    __shared__ ushort Bs[128 * 128];
    const int tid = threadIdx.x;
    const int m0 = blockIdx.x * 128;
    const int n0 = blockIdx.y * 128;

    {   // stage A tile (swizzle group index by row&15)
        const ushort* Ab = A + (size_t)m0 * 128;
        const short8 z8 = {0, 0, 0, 0, 0, 0, 0, 0};
#pragma unroll
        for (int it = 0; it < 16; it++) {
            int idx = tid + it * 256;          // ushort8 slot, 4096 total
            int row = idx >> 4, g = idx & 15;
            short8 v = z8;
            if (m0 + row < M) v = *(const short8*)(Ab + row * 128 + g * 8);
            *(short8*)(&As[row * 128 + ((g ^ (row & 15)) << 3)]) = v;
        }
        const ushort* Bb = BT + (size_t)n0 * 128;
#pragma unroll
        for (int it = 0; it < 16; it++) {
            int idx = tid + it * 256;
            int row = idx >> 4, g = idx & 15;
            short8 v = *(const short8*)(Bb + row * 128 + g * 8);
            *(short8*)(&Bs[row * 128 + ((g ^ (row & 15)) << 3)]) = v;
        }
    }
    __syncthreads();

    const int w = tid >> 6, lane = tid & 63;
    const int wm = (w & 1) * 64, wn = (w >> 1) * 64;
    const int l15 = lane & 15, quad = lane >> 4;

    f32x4 acc[4][4];
    const f32x4 z4 = {0.f, 0.f, 0.f, 0.f};
#pragma unroll
    for (int i = 0; i < 4; i++)
#pragma unroll
        for (int j = 0; j < 4; j++) acc[i][j] = z4;

#pragma unroll
    for (int ks = 0; ks < 128; ks += 32) {
        const int g0 = (ks >> 3) + quad;        // 16B-group of this lane's 8 k's
        short8 af[4], bf[4];
#pragma unroll
        for (int i = 0; i < 4; i++) {
            int row = wm + i * 16 + l15;
            af[i] = *(const short8*)(&As[row * 128 + ((g0 ^ (row & 15)) << 3)]);
        }
#pragma unroll
        for (int j = 0; j < 4; j++) {
            int row = wn + j * 16 + l15;
            bf[j] = *(const short8*)(&Bs[row * 128 + ((g0 ^ (row & 15)) << 3)]);
        }
#pragma unroll
        for (int i = 0; i < 4; i++)
#pragma unroll
            for (int j = 0; j < 4; j++)
                acc[i][j] = __builtin_amdgcn_mfma_f32_16x16x32_bf16(
                    af[i], bf[j], acc[i][j], 0, 0, 0);
    }

    // epilogue: C[m=quad*4+q][n=l15] per 16x16 frag
#pragma unroll
    for (int i = 0; i < 4; i++) {
#pragma unroll
        for (int q = 0; q < 4; q++) {
            int gm = m0 + wm + i * 16 + quad * 4 + q;
            if (gm >= M) continue;
#pragma unroll
            for (int j = 0; j < 4; j++) {
                int gn = n0 + wn + j * 16 + l15;
                if (gn >= ncol) continue;
                float v = acc[i][j][q];
                if (BIAS) v += bias[gn];
                if (RELU) v = v > 0.f ? v : 0.f;
                if (STF) Cf[(size_t)gm * ldc + gn] = v;
                if (STB) Cb[(size_t)gm * ldc + gn] = f2b(v);
            }
        }
    }
}

// ---------------------------------------------------------------------------
// WT[(r*128+f)*128 + k] = bf16( sum_b comp[r][b] * basis[b][k][f] )
// ---------------------------------------------------------------------------
__global__ void build_WT(const float* __restrict__ basis,
                         const float* __restrict__ comp, ushort* __restrict__ WT)
{
    int i = blockIdx.x * 256 + threadIdx.x;
    if (i >= RR * 128 * 128) return;
    int k = i & 127, f = (i >> 7) & 127, r = i >> 14;
    float a = 0.f;
#pragma unroll
    for (int b = 0; b < 4; b++) a += comp[r * 4 + b] * basis[(b * 128 + k) * 128 + f];
    WT[i] = f2b(a);
}

// out[f*128+k] = bf16(in[k*cols+f]) for f<cols else 0   (in: [128][cols])
__global__ void transpose_pad(const float* __restrict__ in, ushort* __restrict__ out,
                              int cols)
{
    int i = blockIdx.x * 256 + threadIdx.x;
    if (i >= 128 * 128) return;
    int k = i & 127, f = i >> 7;
    out[i] = (f < cols) ? f2b(in[k * cols + f]) : (ushort)0;
}

__global__ void cast_bf16(const float* __restrict__ in, ushort* __restrict__ out, int n4)
{
    int i = blockIdx.x * 256 + threadIdx.x;
    if (i >= n4) return;
    float4 v = ((const float4*)in)[i];
    ushort4 o = { f2b(v.x), f2b(v.y), f2b(v.z), f2b(v.w) };
    ((ushort4*)out)[i] = o;
}

// ---------------------------------------------------------------------------
__global__ void count_edges(const int* __restrict__ src, const int* __restrict__ dst,
                            const int* __restrict__ et, int* __restrict__ cnt,
                            int* __restrict__ deg, int E)
{
    int e = blockIdx.x * blockDim.x + threadIdx.x;
    if (e < E) {
        atomicAdd(&cnt[dst[e] * RR + et[e]], 1);
        atomicAdd(&deg[src[e]], 1);
    }
}

// ---------------------------------------------------------------------------
// 3-phase exclusive scan (1024 elements per block)
// ---------------------------------------------------------------------------
__global__ void scan1(const int* __restrict__ in, int* __restrict__ bsum, int n)
{
    __shared__ int s[256];
    const int b = blockIdx.x, t = threadIdx.x;
    const int base = b * 1024;
    int v = 0;
#pragma unroll
    for (int i = 0; i < 4; i++) {
        int idx = base + t * 4 + i;
        if (idx < n) v += in[idx];
    }
    s[t] = v; __syncthreads();
    for (int off = 128; off > 0; off >>= 1) {
        if (t < off) s[t] += s[t + off];
        __syncthreads();
    }
    if (t == 0) bsum[b] = s[0];
}

__global__ void scan_top(int* __restrict__ bsum, int nb)
{
    __shared__ int s[1024];
    const int t = threadIdx.x;
    int v = (t < nb) ? bsum[t] : 0;
    s[t] = v; __syncthreads();
    for (int off = 1; off < 1024; off <<= 1) {
        int x = (t >= off) ? s[t - off] : 0;
        __syncthreads();
        s[t] += x;
        __syncthreads();
    }
    if (t < nb) bsum[t] = s[t] - v;   // exclusive
}

__global__ void scan2(const int* __restrict__ in, const int* __restrict__ bsum,
                      int* __restrict__ out, int n)
{
    __shared__ int s[256];
    const int b = blockIdx.x, t = threadIdx.x;
    const int base = b * 1024;
    int loc[4];
    int v = 0;
#pragma unroll
    for (int i = 0; i < 4; i++) {
        int idx = base + t * 4 + i;
        int x = (idx < n) ? in[idx] : 0;
        loc[i] = v; v += x;
    }
    s[t] = v; __syncthreads();
    for (int off = 1; off < 256; off <<= 1) {
        int x = (t >= off) ? s[t - off] : 0;
        __syncthreads();
        s[t] += x;
        __syncthreads();
    }
    const int add = bsum[b] + (s[t] - v);
#pragma unroll
    for (int i = 0; i < 4; i++) {
        int idx = base + t * 4 + i;
        if (idx < n) out[idx] = add + loc[i];
    }
}

// ---------------------------------------------------------------------------
__global__ void fill_csrA(const int* __restrict__ src, const int* __restrict__ dst,
                          const int* __restrict__ et, const int* __restrict__ aoff,
                          int* __restrict__ acur, int* __restrict__ acsr, int E)
{
    int e = blockIdx.x * blockDim.x + threadIdx.x;
    if (e < E) {
        int seg = dst[e] * RR + et[e];
        int p = aoff[seg] + atomicAdd(&acur[seg], 1);
        acsr[p] = src[e];
    }
}

__global__ void fill_csrG(const int* __restrict__ src, const int* __restrict__ dst,
                          const int* __restrict__ goff, int* __restrict__ gcur,
                          int* __restrict__ gcsr, int E)
{
    int e = blockIdx.x * blockDim.x + threadIdx.x;
    if (e < E) {
        int s0 = src[e];
        int p = goff[s0] + atomicAdd(&gcur[s0], 1);
        gcsr[p] = dst[e];
    }
}

// ---------------------------------------------------------------------------
// gate gather: TAU[n] = tanh( mean over out-edges of (h[n]-h[dst])^2 )
// ---------------------------------------------------------------------------
__global__ __launch_bounds__(256) void gate_gather(
    const float* __restrict__ h, const int* __restrict__ gcsr,
    const int* __restrict__ goff, const int* __restrict__ deg,
    float* __restrict__ TAU, int N)
{
    const int g = threadIdx.x >> 5, lane = threadIdx.x & 31;
    const int n = blockIdx.x * 8 + g;
    if (n >= N) return;
    const int start = goff[n];
    const int c = deg[n];
    const float4 a = *(const float4*)(h + (size_t)n * D + lane * 4);
    float4 acc = {0.f, 0.f, 0.f, 0.f};
    for (int i = 0; i < c; i++) {
        int d = gcsr[start + i];
        const float4 b = *(const float4*)(h + (size_t)d * D + lane * 4);
        float dx = a.x - b.x, dy = a.y - b.y, dz = a.z - b.z, dw = a.w - b.w;
        acc.x += dx * dx; acc.y += dy * dy; acc.z += dz * dz; acc.w += dw * dw;
    }
    const float inv = (c > 0) ? (1.f / (float)c) : 1.f;
    float4 t;
    t.x = tanhf(acc.x * inv); t.y = tanhf(acc.y * inv);
    t.z = tanhf(acc.z * inv); t.w = tanhf(acc.w * inv);
    *(float4*)(TAU + (size_t)n * D + lane * 4) = t;
}

// ---------------------------------------------------------------------------
// hn[n] += sum_{rr<Rc} mean_{e in seg(n,r0+rr)} Y[src_e][rr*128 + f]
// Y is bf16 [M][ldY]; single-owner RMW, no atomics.
// ---------------------------------------------------------------------------
__global__ __launch_bounds__(256) void rgcn_gather_all(
    const ushort* __restrict__ Y, const int* __restrict__ acsr,
    const int* __restrict__ aoff, const int* __restrict__ cnt,
    float* __restrict__ hn, int r0, int Rc, int ldY, int N)
{
    const int g = threadIdx.x >> 5, lane = threadIdx.x & 31;
    const int n = blockIdx.x * 8 + g;
    if (n >= N) return;
    float4 acc = {0.f, 0.f, 0.f, 0.f};
    bool any = false;
    for (int rr = 0; rr < Rc; rr++) {
        const int seg = n * RR + r0 + rr;
        const int c = cnt[seg];
        if (c == 0) continue;
        any = true;
        const int st = aoff[seg];
        float4 s = {0.f, 0.f, 0.f, 0.f};
        const ushort* Yc = Y + rr * 128 + lane * 4;
        for (int i = 0; i < c; i++) {
            int s0 = acsr[st + i];
            ushort4 y = *(const ushort4*)(Yc + (size_t)s0 * ldY);
            s.x += b2f(y.x); s.y += b2f(y.y); s.z += b2f(y.z); s.w += b2f(y.w);
        }
        const float inv = 1.f / (float)c;
        acc.x += s.x * inv; acc.y += s.y * inv;
        acc.z += s.z * inv; acc.w += s.w * inv;
    }
    if (any) {
        float* p = hn + (size_t)n * D + lane * 4;
        float4 cur = *(float4*)p;
        cur.x += acc.x; cur.y += acc.y; cur.z += acc.z; cur.w += acc.w;
        *(float4*)p = cur;
    }
}

// ---------------------------------------------------------------------------
// h_next = (1-tau)*h + tau*relu(acc); also emit bf16 copy for next GEMM
// ---------------------------------------------------------------------------
__global__ void finalize(const float* __restrict__ hp, float* __restrict__ hn,
                         const float* __restrict__ TAU, ushort* __restrict__ hb,
                         int total4)
{
    int idx = blockIdx.x * blockDim.x + threadIdx.x;
    if (idx >= total4) return;
    const float4 p = ((const float4*)hp)[idx];
    float4 a = ((float4*)hn)[idx];
    const float4 t = ((const float4*)TAU)[idx];
    float4 o;
    a.x = a.x > 0.f ? a.x : 0.f; o.x = p.x + t.x * (a.x - p.x);
    a.y = a.y > 0.f ? a.y : 0.f; o.y = p.y + t.y * (a.y - p.y);
    a.z = a.z > 0.f ? a.z : 0.f; o.z = p.z + t.z * (a.z - p.z);
    a.w = a.w > 0.f ? a.w : 0.f; o.w = p.w + t.w * (a.w - p.w);
    ((float4*)hn)[idx] = o;
    ushort4 ob = { f2b(o.x), f2b(o.y), f2b(o.z), f2b(o.w) };
    ((ushort4*)hb)[idx] = ob;
}

// ---------------------------------------------------------------------------
extern "C" void kernel_launch(void* const* d_in, const int* in_sizes, int n_in,
                              void* d_out, int out_size, void* d_ws, size_t ws_size,
                              hipStream_t stream)
{
    const float* x      = (const float*)d_in[0];
    const int*   src    = (const int*)  d_in[1];
    const int*   dst    = (const int*)  d_in[2];
    const int*   etyp   = (const int*)  d_in[3];
    const float* projW  = (const float*)d_in[4];
    const float* projb  = (const float*)d_in[5];
    const float* basis1 = (const float*)d_in[6];
    const float* comp1  = (const float*)d_in[7];
    const float* root1  = (const float*)d_in[8];
    const float* bias1  = (const float*)d_in[9];
    const float* basis2 = (const float*)d_in[10];
    const float* comp2  = (const float*)d_in[11];
    const float* root2  = (const float*)d_in[12];
    const float* bias2  = (const float*)d_in[13];
    const float* outW   = (const float*)d_in[14];
    const float* outb   = (const float*)d_in[15];

    const int N    = in_sizes[0] / D;
    const int E    = in_sizes[1];
    const int OUTD = in_sizes[15];

    float* out  = (float*)d_out;
    float* lat0 = out + (size_t)N * OUTD;
    float* lat1 = lat0 + (size_t)N * D;
    float* lat2 = lat1 + (size_t)N * D;

    // ---- workspace: fixed part sizes ----
    const size_t szTAU  = (size_t)N * D * 4;
    const size_t szHB   = (size_t)N * D * 2;
    const size_t szWT   = (size_t)327680 * 2;            // proj/root1/root2/out (4*16K) + W1T/W2T (2*128K)
    const size_t szCNT  = (size_t)(N * RR + N) * 4 * 2;  // cnt,deg + acur,gcur
    const size_t szOFF  = (size_t)(N * RR + N) * 4;      // aoff, goff
    const size_t szCSR  = (size_t)E * 4 * 2;
    const size_t szBS   = 4096;
    const size_t fixed  = szTAU + szHB + szWT + szCNT + szOFF + szCSR + szBS;

    int Rc = 0;
    for (int c = RR; c >= 1; c >>= 1)
        if (fixed + (size_t)N * c * 128 * 2 <= ws_size) { Rc = c; break; }
    if (Rc == 0) return;   // fails loudly via poisoned d_out
    const int ldY = Rc * 128;

    char* p = (char*)d_ws;
    float*  TAU = (float*)p;          p += szTAU;
    ushort* Yb  = (ushort*)p;         p += (size_t)N * ldY * 2;
    ushort* hb  = (ushort*)p;         p += szHB;
    ushort* WT  = (ushort*)p;         p += szWT;
    int* cnt_i  = (int*)p;            p += (size_t)N * RR * 4;
    int* deg_i  = (int*)p;            p += (size_t)N * 4;
    int* acur   = (int*)p;            p += (size_t)N * RR * 4;
    int* gcur   = (int*)p;            p += (size_t)N * 4;
    int* aoff   = (int*)p;            p += (size_t)N * RR * 4;
    int* goff   = (int*)p;            p += (size_t)N * 4;
    int* acsr   = (int*)p;            p += (size_t)E * 4;
    int* gcsr   = (int*)p;            p += (size_t)E * 4;
    int* bsum   = (int*)p;

    ushort* projWT = WT;
    ushort* root1T = WT + 16384;
    ushort* root2T = WT + 32768;
    ushort* outWT  = WT + 49152;
    ushort* W1T    = WT + 65536;
    ushort* W2T    = WT + 65536 + 131072;

    // zero counters (cnt_i, deg_i, acur, gcur contiguous)
    hipMemsetAsync(cnt_i, 0, szCNT, stream);

    // weight prep (bf16, transposed [n][k])
    build_WT<<<512, 256, 0, stream>>>(basis1, comp1, W1T);
    build_WT<<<512, 256, 0, stream>>>(basis2, comp2, W2T);
    transpose_pad<<<64, 256, 0, stream>>>(projW, projWT, 128);
    transpose_pad<<<64, 256, 0, stream>>>(root1, root1T, 128);
    transpose_pad<<<64, 256, 0, stream>>>(root2, root2T, 128);
    transpose_pad<<<64, 256, 0, stream>>>(outW, outWT, OUTD);

    // cast x -> bf16 (into hb; proj GEMM reads it and overwrites in-place)
    cast_bf16<<<(N * 32 + 255) / 256, 256, 0, stream>>>(x, hb, N * 32);

    count_edges<<<(E + 255) / 256, 256, 0, stream>>>(src, dst, etyp, cnt_i, deg_i, E);

    {   // exclusive scans -> CSR offsets
        int n1 = N * RR, nb1 = (n1 + 1023) / 1024;
        scan1<<<nb1, 256, 0, stream>>>(cnt_i, bsum, n1);
        scan_top<<<1, 1024, 0, stream>>>(bsum, nb1);
        scan2<<<nb1, 256, 0, stream>>>(cnt_i, bsum, aoff, n1);
        int nb2 = (N + 1023) / 1024;
        scan1<<<nb2, 256, 0, stream>>>(deg_i, bsum, N);
        scan_top<<<1, 1024, 0, stream>>>(bsum, nb2);
        scan2<<<nb2, 256, 0, stream>>>(deg_i, bsum, goff, N);
    }

    fill_csrA<<<(E + 255) / 256, 256, 0, stream>>>(src, dst, etyp, aoff, acur, acsr, E);
    fill_csrG<<<(E + 255) / 256, 256, 0, stream>>>(src, dst, goff, gcur, gcsr, E);

    const int mb = (N + 127) / 128;
    const int nodeblocks = (N + 7) / 8;

    // proj: lat0 = relu(x @ projW + projb), bf16 copy -> hb (in-place safe, gridDim.y==1)
    gemm_bf16<true, true, true, true><<<dim3(mb, 1), 256, 0, stream>>>(
        hb, projWT, projb, lat0, hb, N, 128, 128);

    const ushort* WsT[2]   = {W1T, W2T};
    const ushort* rootT[2] = {root1T, root2T};
    const float* biases[2] = {bias1, bias2};
    float* lats[3]         = {lat0, lat1, lat2};

    for (int l = 0; l < 2; l++) {
        const float* h = lats[l];
        float* hn = lats[l + 1];

        gate_gather<<<nodeblocks, 256, 0, stream>>>(h, gcsr, goff, deg_i, TAU, N);

        // hn = h @ root + bias  (fp32 accumulator init)
        gemm_bf16<true, false, true, false><<<dim3(mb, 1), 256, 0, stream>>>(
            hb, rootT[l], biases[l], hn, nullptr, N, 128, 128);

        for (int r0 = 0; r0 < RR; r0 += Rc) {
            // Y[:, 0..Rc*128) = h @ [W_{r0} .. W_{r0+Rc-1}]  (bf16 out)
            gemm_bf16<false, false, false, true><<<dim3(mb, Rc), 256, 0, stream>>>(
                hb, WsT[l] + (size_t)r0 * 128 * 128, nullptr, nullptr, Yb, N, ldY, ldY);
            rgcn_gather_all<<<nodeblocks, 256, 0, stream>>>(
                Yb, acsr, aoff, cnt_i, hn, r0, Rc, ldY, N);
        }

        finalize<<<(N * 32 + 255) / 256, 256, 0, stream>>>(h, hn, TAU, hb, N * 32);
    }

    // out = lat2 @ outW + outb   (ldc = OUTD, store cols < OUTD)
    gemm_bf16<true, false, true, false><<<dim3(mb, 1), 256, 0, stream>>>(
        hb, outWT, outb, out, nullptr, N, OUTD, OUTD);
}

// Round 4
// 1468.143 us; speedup vs baseline: 8.3682x; 1.1366x over previous
//
#include <hip/hip_runtime.h>
#include <cstdint>
#include <cstddef>

#define D 128
#define RR 8
#define LDA 1152   // Abig row: 8*128 agg + 128 h

typedef __attribute__((ext_vector_type(8))) short short8;
typedef __attribute__((ext_vector_type(4))) float f32x4;

__device__ inline ushort f2b(float x) {
    union { float f; unsigned u; } v; v.f = x;
    unsigned r = v.u + 0x7fff + ((v.u >> 16) & 1);
    return (ushort)(r >> 16);
}
__device__ inline float b2f(ushort u) {
    union { unsigned u; float f; } v; v.u = ((unsigned)u) << 16; return v.f;
}

// ---------------------------------------------------------------------------
// bf16 MFMA GEMM: C[M, ncol] = A[M, ktiles*128] @ B (+bias) (+relu)
// A: [M][lda] bf16 (lda mult of 8).  BT: [128][ktiles*128] bf16, row = out col.
// 256 threads = 4 waves; block tile 128(M) x 128(N); K-loop over 128-chunks.
// LDS XOR-swizzled on 16B groups. In-place A==Cb safe (reads staged pre-store).
// ---------------------------------------------------------------------------
template<bool BIAS, bool RELU, bool STF, bool STB>
__global__ __launch_bounds__(256) void gemm_bf16(
    const ushort* __restrict__ A, int lda, const ushort* __restrict__ BT, int ktiles,
    const float* __restrict__ bias, float* __restrict__ Cf, int ldcf,
    ushort* __restrict__ Cb, int ldcb, int M, int ncol)
{
    __shared__ ushort As[128 * 128];
    __shared__ ushort Bs[128 * 128];
    const int tid = threadIdx.x;
    const int m0 = blockIdx.x * 128;
    const int ldb = ktiles * 128;

    const int w = tid >> 6, lane = tid & 63;
    const int wm = (w & 1) * 64, wn = (w >> 1) * 64;
    const int l15 = lane & 15, quad = lane >> 4;

    f32x4 acc[4][4];
    const f32x4 z4 = {0.f, 0.f, 0.f, 0.f};
#pragma unroll
    for (int i = 0; i < 4; i++)
#pragma unroll
        for (int j = 0; j < 4; j++) acc[i][j] = z4;

    for (int kt = 0; kt < ktiles; kt++) {
        const short8 z8 = {0, 0, 0, 0, 0, 0, 0, 0};
#pragma unroll
        for (int it = 0; it < 16; it++) {
            int idx = tid + it * 256;          // ushort8 slot, 4096 total
            int row = idx >> 4, g = idx & 15;
            short8 v = z8;
            if (m0 + row < M)
                v = *(const short8*)(A + (size_t)(m0 + row) * lda + kt * 128 + g * 8);
            *(short8*)(&As[row * 128 + ((g ^ (row & 15)) << 3)]) = v;
        }
#pragma unroll
        for (int it = 0; it < 16; it++) {
            int idx = tid + it * 256;
            int row = idx >> 4, g = idx & 15;
            short8 v = *(const short8*)(BT + (size_t)row * ldb + kt * 128 + g * 8);
            *(short8*)(&Bs[row * 128 + ((g ^ (row & 15)) << 3)]) = v;
        }
        __syncthreads();

#pragma unroll
        for (int ks = 0; ks < 128; ks += 32) {
            const int g0 = (ks >> 3) + quad;
            short8 af[4], bf[4];
#pragma unroll
            for (int i = 0; i < 4; i++) {
                int row = wm + i * 16 + l15;
                af[i] = *(const short8*)(&As[row * 128 + ((g0 ^ (row & 15)) << 3)]);
            }
#pragma unroll
            for (int j = 0; j < 4; j++) {
                int row = wn + j * 16 + l15;
                bf[j] = *(const short8*)(&Bs[row * 128 + ((g0 ^ (row & 15)) << 3)]);
            }
#pragma unroll
            for (int i = 0; i < 4; i++)
#pragma unroll
                for (int j = 0; j < 4; j++)
                    acc[i][j] = __builtin_amdgcn_mfma_f32_16x16x32_bf16(
                        af[i], bf[j], acc[i][j], 0, 0, 0);
        }
        __syncthreads();
    }

    // epilogue: C[m=quad*4+q][n=l15] per 16x16 frag
#pragma unroll
    for (int i = 0; i < 4; i++) {
#pragma unroll
        for (int q = 0; q < 4; q++) {
            int gm = m0 + wm + i * 16 + quad * 4 + q;
            if (gm >= M) continue;
#pragma unroll
            for (int j = 0; j < 4; j++) {
                int gn = wn + j * 16 + l15;
                if (gn >= ncol) continue;
                float v = acc[i][j][q];
                if (BIAS) v += bias[gn];
                if (RELU) v = v > 0.f ? v : 0.f;
                if (STF) Cf[(size_t)gm * ldcf + gn] = v;
                if (STB) Cb[(size_t)gm * ldcb + gn] = f2b(v);
            }
        }
    }
}

// ---------------------------------------------------------------------------
// bigBT[f][c]: c<1024 -> W_{c>>7}[c&127][f];  c>=1024 -> root[c-1024][f]
// ---------------------------------------------------------------------------
__global__ void build_bigBT(const float* __restrict__ basis,
                            const float* __restrict__ comp,
                            const float* __restrict__ root,
                            ushort* __restrict__ BT)
{
    int i = blockIdx.x * 256 + threadIdx.x;
    if (i >= 128 * LDA) return;
    int f = i / LDA, c = i - f * LDA;
    float a;
    if (c < 1024) {
        int r = c >> 7, d = c & 127;
        a = 0.f;
#pragma unroll
        for (int b = 0; b < 4; b++)
            a += comp[r * 4 + b] * basis[(b * 128 + d) * 128 + f];
    } else {
        a = root[(c - 1024) * 128 + f];
    }
    BT[i] = f2b(a);
}

// out[f*128+k] = bf16(in[k*cols+f]) for f<cols else 0   (in: [128][cols])
__global__ void transpose_pad(const float* __restrict__ in, ushort* __restrict__ out,
                              int cols)
{
    int i = blockIdx.x * 256 + threadIdx.x;
    if (i >= 128 * 128) return;
    int k = i & 127, f = i >> 7;
    out[i] = (f < cols) ? f2b(in[k * cols + f]) : (ushort)0;
}

// x [N][128] fp32 -> Abig h-block bf16
__global__ void cast_x(const float* __restrict__ in, ushort* __restrict__ Abig, int total4)
{
    int i = blockIdx.x * 256 + threadIdx.x;
    if (i >= total4) return;
    int n = i >> 5, q = i & 31;
    float4 v = ((const float4*)in)[i];
    ushort4 o = { f2b(v.x), f2b(v.y), f2b(v.z), f2b(v.w) };
    *(ushort4*)(Abig + (size_t)n * LDA + 1024 + q * 4) = o;
}

// ---------------------------------------------------------------------------
__global__ void count_edges(const int* __restrict__ src, const int* __restrict__ dst,
                            const int* __restrict__ et, int* __restrict__ cnt,
                            int* __restrict__ deg, int E)
{
    int e0 = (blockIdx.x * 256 + threadIdx.x) * 4;
#pragma unroll
    for (int j = 0; j < 4; j++) {
        int e = e0 + j;
        if (e < E) {
            atomicAdd(&cnt[dst[e] * RR + et[e]], 1);
            atomicAdd(&deg[src[e]], 1);
        }
    }
}

// ---------------------------------------------------------------------------
// 3-phase exclusive scan (1024 elements per block)
// ---------------------------------------------------------------------------
__global__ void scan1(const int* __restrict__ in, int* __restrict__ bsum, int n)
{
    __shared__ int s[256];
    const int b = blockIdx.x, t = threadIdx.x;
    const int base = b * 1024;
    int v = 0;
#pragma unroll
    for (int i = 0; i < 4; i++) {
        int idx = base + t * 4 + i;
        if (idx < n) v += in[idx];
    }
    s[t] = v; __syncthreads();
    for (int off = 128; off > 0; off >>= 1) {
        if (t < off) s[t] += s[t + off];
        __syncthreads();
    }
    if (t == 0) bsum[b] = s[0];
}

__global__ void scan_top(int* __restrict__ bsum, int nb)
{
    __shared__ int s[1024];
    const int t = threadIdx.x;
    int v = (t < nb) ? bsum[t] : 0;
    s[t] = v; __syncthreads();
    for (int off = 1; off < 1024; off <<= 1) {
        int x = (t >= off) ? s[t - off] : 0;
        __syncthreads();
        s[t] += x;
        __syncthreads();
    }
    if (t < nb) bsum[t] = s[t] - v;   // exclusive
}

__global__ void scan2(const int* __restrict__ in, const int* __restrict__ bsum,
                      int* __restrict__ out, int n)
{
    __shared__ int s[256];
    const int b = blockIdx.x, t = threadIdx.x;
    const int base = b * 1024;
    int loc[4];
    int v = 0;
#pragma unroll
    for (int i = 0; i < 4; i++) {
        int idx = base + t * 4 + i;
        int x = (idx < n) ? in[idx] : 0;
        loc[i] = v; v += x;
    }
    s[t] = v; __syncthreads();
    for (int off = 1; off < 256; off <<= 1) {
        int x = (t >= off) ? s[t - off] : 0;
        __syncthreads();
        s[t] += x;
        __syncthreads();
    }
    const int add = bsum[b] + (s[t] - v);
#pragma unroll
    for (int i = 0; i < 4; i++) {
        int idx = base + t * 4 + i;
        if (idx < n) out[idx] = add + loc[i];
    }
}

// ---------------------------------------------------------------------------
// both CSR fills in one pass
// ---------------------------------------------------------------------------
__global__ void fill_both(const int* __restrict__ src, const int* __restrict__ dst,
                          const int* __restrict__ et,
                          const int* __restrict__ aoff, int* __restrict__ acur,
                          int* __restrict__ acsr,
                          const int* __restrict__ goff, int* __restrict__ gcur,
                          int* __restrict__ gcsr, int E)
{
    int e0 = (blockIdx.x * 256 + threadIdx.x) * 4;
#pragma unroll
    for (int j = 0; j < 4; j++) {
        int e = e0 + j;
        if (e < E) {
            int s0 = src[e], d0 = dst[e];
            int seg = d0 * RR + et[e];
            int p = aoff[seg] + atomicAdd(&acur[seg], 1);
            acsr[p] = s0;
            int pg = goff[s0] + atomicAdd(&gcur[s0], 1);
            gcsr[pg] = d0;
        }
    }
}

// ---------------------------------------------------------------------------
// gate gather (bf16 h): TAUb[n] = bf16(tanh( mean_out-edges (h[n]-h[dst])^2 ))
// ---------------------------------------------------------------------------
__global__ __launch_bounds__(256) void gate_gather(
    const ushort* __restrict__ Abig, const int* __restrict__ gcsr,
    const int* __restrict__ goff, const int* __restrict__ deg,
    ushort* __restrict__ TAUb, int N)
{
    const int g = threadIdx.x >> 5, lane = threadIdx.x & 31;
    const int n = blockIdx.x * 8 + g;
    if (n >= N) return;
    const int start = goff[n];
    const int c = deg[n];
    const ushort* hbase = Abig + 1024 + lane * 4;
    ushort4 a4 = *(const ushort4*)(hbase + (size_t)n * LDA);
    float ax = b2f(a4.x), ay = b2f(a4.y), az = b2f(a4.z), aw = b2f(a4.w);
    float4 acc = {0.f, 0.f, 0.f, 0.f};
    int i = 0;
    for (; i + 2 <= c; i += 2) {
        int d0 = gcsr[start + i], d1 = gcsr[start + i + 1];
        ushort4 b0 = *(const ushort4*)(hbase + (size_t)d0 * LDA);
        ushort4 b1 = *(const ushort4*)(hbase + (size_t)d1 * LDA);
        float dx = ax - b2f(b0.x), dy = ay - b2f(b0.y),
              dz = az - b2f(b0.z), dw = aw - b2f(b0.w);
        acc.x += dx * dx; acc.y += dy * dy; acc.z += dz * dz; acc.w += dw * dw;
        dx = ax - b2f(b1.x); dy = ay - b2f(b1.y);
        dz = az - b2f(b1.z); dw = aw - b2f(b1.w);
        acc.x += dx * dx; acc.y += dy * dy; acc.z += dz * dz; acc.w += dw * dw;
    }
    if (i < c) {
        int d0 = gcsr[start + i];
        ushort4 b0 = *(const ushort4*)(hbase + (size_t)d0 * LDA);
        float dx = ax - b2f(b0.x), dy = ay - b2f(b0.y),
              dz = az - b2f(b0.z), dw = aw - b2f(b0.w);
        acc.x += dx * dx; acc.y += dy * dy; acc.z += dz * dz; acc.w += dw * dw;
    }
    const float inv = (c > 0) ? (1.f / (float)c) : 1.f;
    ushort4 t;
    t.x = f2b(tanhf(acc.x * inv)); t.y = f2b(tanhf(acc.y * inv));
    t.z = f2b(tanhf(acc.z * inv)); t.w = f2b(tanhf(acc.w * inv));
    *(ushort4*)(TAUb + (size_t)n * D + lane * 4) = t;
}

// ---------------------------------------------------------------------------
// agg gather: Abig[n][r*128+f] = mean_{e in seg(n,r)} h_bf16[src_e][f]  (0 if empty)
// one 32-lane group per segment
// ---------------------------------------------------------------------------
__global__ __launch_bounds__(256) void agg_gather(
    ushort* __restrict__ Abig, const int* __restrict__ acsr,
    const int* __restrict__ aoff, const int* __restrict__ cnt, int Nseg)
{
    const int g = threadIdx.x >> 5, lane = threadIdx.x & 31;
    const int s = blockIdx.x * 8 + g;
    if (s >= Nseg) return;
    const int n = s >> 3, r = s & 7;
    const int c = cnt[s];
    ushort4 outv = {0, 0, 0, 0};
    if (c > 0) {
        const int st = aoff[s];
        const ushort* hbase = Abig + 1024 + lane * 4;
        float4 acc = {0.f, 0.f, 0.f, 0.f};
        int i = 0;
        for (; i + 2 <= c; i += 2) {
            int s0 = acsr[st + i], s1 = acsr[st + i + 1];
            ushort4 y0 = *(const ushort4*)(hbase + (size_t)s0 * LDA);
            ushort4 y1 = *(const ushort4*)(hbase + (size_t)s1 * LDA);
            acc.x += b2f(y0.x) + b2f(y1.x); acc.y += b2f(y0.y) + b2f(y1.y);
            acc.z += b2f(y0.z) + b2f(y1.z); acc.w += b2f(y0.w) + b2f(y1.w);
        }
        if (i < c) {
            int s0 = acsr[st + i];
            ushort4 y0 = *(const ushort4*)(hbase + (size_t)s0 * LDA);
            acc.x += b2f(y0.x); acc.y += b2f(y0.y);
            acc.z += b2f(y0.z); acc.w += b2f(y0.w);
        }
        const float inv = 1.f / (float)c;
        outv.x = f2b(acc.x * inv); outv.y = f2b(acc.y * inv);
        outv.z = f2b(acc.z * inv); outv.w = f2b(acc.w * inv);
    }
    *(ushort4*)(Abig + (size_t)n * LDA + r * 128 + lane * 4) = outv;
}

// ---------------------------------------------------------------------------
// h_next = (1-tau)*h + tau*hn  (hn already relu'd by GEMM epilogue);
// writes fp32 hn and bf16 into Abig h-block
// ---------------------------------------------------------------------------
__global__ void finalize(const float* __restrict__ hp, float* __restrict__ hn,
                         const ushort* __restrict__ TAUb, ushort* __restrict__ Abig,
                         int total4)
{
    int idx = blockIdx.x * 256 + threadIdx.x;
    if (idx >= total4) return;
    int n = idx >> 5, q = idx & 31;
    const float4 p = ((const float4*)hp)[idx];
    const float4 a = ((const float4*)hn)[idx];
    const ushort4 t4 = ((const ushort4*)TAUb)[idx];
    float4 o;
    o.x = p.x + b2f(t4.x) * (a.x - p.x);
    o.y = p.y + b2f(t4.y) * (a.y - p.y);
    o.z = p.z + b2f(t4.z) * (a.z - p.z);
    o.w = p.w + b2f(t4.w) * (a.w - p.w);
    ((float4*)hn)[idx] = o;
    ushort4 ob = { f2b(o.x), f2b(o.y), f2b(o.z), f2b(o.w) };
    *(ushort4*)(Abig + (size_t)n * LDA + 1024 + q * 4) = ob;
}

// ---------------------------------------------------------------------------
extern "C" void kernel_launch(void* const* d_in, const int* in_sizes, int n_in,
                              void* d_out, int out_size, void* d_ws, size_t ws_size,
                              hipStream_t stream)
{
    const float* x      = (const float*)d_in[0];
    const int*   src    = (const int*)  d_in[1];
    const int*   dst    = (const int*)  d_in[2];
    const int*   etyp   = (const int*)  d_in[3];
    const float* projW  = (const float*)d_in[4];
    const float* projb  = (const float*)d_in[5];
    const float* basis1 = (const float*)d_in[6];
    const float* comp1  = (const float*)d_in[7];
    const float* root1  = (const float*)d_in[8];
    const float* bias1  = (const float*)d_in[9];
    const float* basis2 = (const float*)d_in[10];
    const float* comp2  = (const float*)d_in[11];
    const float* root2  = (const float*)d_in[12];
    const float* bias2  = (const float*)d_in[13];
    const float* outW   = (const float*)d_in[14];
    const float* outb   = (const float*)d_in[15];

    const int N    = in_sizes[0] / D;
    const int E    = in_sizes[1];
    const int OUTD = in_sizes[15];

    float* out  = (float*)d_out;
    float* lat0 = out + (size_t)N * OUTD;
    float* lat1 = lat0 + (size_t)N * D;
    float* lat2 = lat1 + (size_t)N * D;

    // ---- workspace layout ----
    char* p = (char*)d_ws;
    ushort* Abig  = (ushort*)p;  p += (size_t)N * LDA * 2;
    ushort* TAUb  = (ushort*)p;  p += (size_t)N * D * 2;
    ushort* projWT = (ushort*)p; p += 16384 * 2;
    ushort* outWT  = (ushort*)p; p += 16384 * 2;
    ushort* bigBT1 = (ushort*)p; p += (size_t)128 * LDA * 2;
    ushort* bigBT2 = (ushort*)p; p += (size_t)128 * LDA * 2;
    int* cnt_i  = (int*)p;       p += (size_t)N * RR * 4;
    int* deg_i  = (int*)p;       p += (size_t)N * 4;
    int* acur   = (int*)p;       p += (size_t)N * RR * 4;
    int* gcur   = (int*)p;       p += (size_t)N * 4;
    int* aoff   = (int*)p;       p += (size_t)N * RR * 4;
    int* goff   = (int*)p;       p += (size_t)N * 4;
    int* acsr   = (int*)p;       p += (size_t)E * 4;
    int* gcsr   = (int*)p;       p += (size_t)E * 4;
    int* bsum   = (int*)p;       p += 4096;

    if ((size_t)(p - (char*)d_ws) > ws_size) return;  // fails loudly

    // zero counters (cnt_i, deg_i, acur, gcur contiguous)
    hipMemsetAsync(cnt_i, 0, sizeof(int) * 2 * ((size_t)N * RR + N), stream);

    // weight prep
    build_bigBT<<<(128 * LDA + 255) / 256, 256, 0, stream>>>(basis1, comp1, root1, bigBT1);
    build_bigBT<<<(128 * LDA + 255) / 256, 256, 0, stream>>>(basis2, comp2, root2, bigBT2);
    transpose_pad<<<64, 256, 0, stream>>>(projW, projWT, 128);
    transpose_pad<<<64, 256, 0, stream>>>(outW, outWT, OUTD);

    cast_x<<<(N * 32 + 255) / 256, 256, 0, stream>>>(x, Abig, N * 32);

    count_edges<<<(E / 4 + 255) / 256, 256, 0, stream>>>(src, dst, etyp, cnt_i, deg_i, E);

    {   // exclusive scans -> CSR offsets
        int n1 = N * RR, nb1 = (n1 + 1023) / 1024;
        scan1<<<nb1, 256, 0, stream>>>(cnt_i, bsum, n1);
        scan_top<<<1, 1024, 0, stream>>>(bsum, nb1);
        scan2<<<nb1, 256, 0, stream>>>(cnt_i, bsum, aoff, n1);
        int nb2 = (N + 1023) / 1024;
        scan1<<<nb2, 256, 0, stream>>>(deg_i, bsum, N);
        scan_top<<<1, 1024, 0, stream>>>(bsum, nb2);
        scan2<<<nb2, 256, 0, stream>>>(deg_i, bsum, goff, N);
    }

    fill_both<<<(E / 4 + 255) / 256, 256, 0, stream>>>(
        src, dst, etyp, aoff, acur, acsr, goff, gcur, gcsr, E);

    const int mb = (N + 127) / 128;
    const int nodeblocks = (N + 7) / 8;
    const int segblocks = (N * RR + 7) / 8;

    // proj: lat0 = relu(x @ projW + projb); bf16 -> Abig h-block (in-place safe)
    gemm_bf16<true, true, true, true><<<mb, 256, 0, stream>>>(
        Abig + 1024, LDA, projWT, 1, projb, lat0, 128, Abig + 1024, LDA, N, 128);

    const ushort* bigBT[2] = {bigBT1, bigBT2};
    const float* biases[2] = {bias1, bias2};
    float* lats[3]         = {lat0, lat1, lat2};

    for (int l = 0; l < 2; l++) {
        float* hn = lats[l + 1];

        gate_gather<<<nodeblocks, 256, 0, stream>>>(Abig, gcsr, goff, deg_i, TAUb, N);
        agg_gather<<<segblocks, 256, 0, stream>>>(Abig, acsr, aoff, cnt_i, N * RR);

        // hn = relu(Abig @ [W_1..W_8; root] + bias)
        gemm_bf16<true, true, true, false><<<mb, 256, 0, stream>>>(
            Abig, LDA, bigBT[l], 9, biases[l], hn, 128, nullptr, 0, N, 128);

        finalize<<<(N * 32 + 255) / 256, 256, 0, stream>>>(
            lats[l], hn, TAUb, Abig, N * 32);
    }

    // out = lat2 @ outW + outb
    gemm_bf16<true, false, true, false><<<mb, 256, 0, stream>>>(
        Abig + 1024, LDA, outWT, 1, outb, out, OUTD, nullptr, 0, N, OUTD);
}